// Round 7
// baseline (505.165 us; speedup 1.0000x reference)
//
#include <hip/hip_runtime.h>
#include <stdint.h>

// AttentionReadout: G=1024 x N=64, D=512, H=8, hd=64. fp32 I/O, bf16 MFMA.
// v7: 2 blocks/CU (4 waves/SIMD). LDS cut to ~69 KB by overlaying the v/P
// scratch onto the x slab after x's last use (1 extra barrier). QKV split:
// pass-A (q,k), scores+softmax (P packed bf16 in regs), pass-B (v), then
// vT/P LDS roundtrip in XOR-swizzled stride-64 scratch (conflict-free).
// __launch_bounds__(512,4) -> 128 VGPR cap. v6 lesson: 2 waves/SIMD +
// phase-aligned waves = all pipes <19% busy.

typedef __attribute__((ext_vector_type(8))) short short8;   // 8 bf16
typedef __attribute__((ext_vector_type(4))) float f32x4;    // MFMA C/D frag

#define D_ 512

// ---- ws layout (bytes) ----
#define WQKV_OFF   0u          // 1536*512 bf16 = 1572864
#define WO_OFF     1572864u    // 512*512 bf16  = 524288
#define UPART_OFF  2097152u    // 16*512 f32    = 32768
#define U_OFF      2129920u    // 512 f32       = 2048
#define C0_OFF     2131968u    // 64
#define SG_OFF     2132032u    // 1024 f32      = 4096
#define WCTX_OFF   2136128u    // 1024*512 bf16 = 1 MB (16B aligned)

__device__ __forceinline__ unsigned short f2bf(float f) {
    union { float f; unsigned int u; } t; t.f = f;
    unsigned int u = t.u;
    return (unsigned short)((u + 0x7FFFu + ((u >> 16) & 1u)) >> 16);  // RNE
}
__device__ __forceinline__ unsigned pack2(float a, float b) {
    return (unsigned)f2bf(a) | ((unsigned)f2bf(b) << 16);
}
// swizzled scratch addr: row-major [64][64] b16, 16B-chunk XOR swizzle
__device__ __forceinline__ int swz(int r, int m) {
    return r*64 + ((((m >> 3) ^ (r & 7)) << 3) | (m & 7));
}

// ---- pre-pass 1 (merged): blocks 0..1023 convert weights; 1024..1039 u-partials ----
__global__ __launch_bounds__(256)
void convert_and_u(const float* __restrict__ wqkv, const float* __restrict__ wo,
                   const float* __restrict__ gw,
                   unsigned short* __restrict__ wbf, float* __restrict__ upart) {
    const int b = blockIdx.x;
    const int t = threadIdx.x;
    if (b < 1024) {
        const int i4 = b * 256 + t;          // 262144 float4 total
        float4 v;
        if (i4 < 196608) v = *(const float4*)(wqkv + (size_t)i4 * 4);
        else             v = *(const float4*)(wo   + (size_t)(i4 - 196608) * 4);
        uint2 p; p.x = pack2(v.x, v.y); p.y = pack2(v.z, v.w);
        *(uint2*)(wbf + (size_t)i4 * 4) = p;
    } else {
        const int bb = b - 1024;             // 16 blocks
        float a0 = 0.f, a1 = 0.f;
        #pragma unroll 4
        for (int e = bb * 32; e < bb * 32 + 32; ++e) {
            const float ge = gw[e];
            a0 += wo[(size_t)e * 512 + t]       * ge;
            a1 += wo[(size_t)e * 512 + t + 256] * ge;
        }
        upart[bb * 512 + t] = a0; upart[bb * 512 + t + 256] = a1;
    }
}

// ---- pre-pass 2: u = sum partials; c0 = bo.gw + gb ----
__global__ __launch_bounds__(256)
void finalize_u(const float* __restrict__ upart, const float* __restrict__ bo,
                const float* __restrict__ gw, const float* __restrict__ gb,
                float* __restrict__ u, float* __restrict__ c0) {
    const int t = threadIdx.x;
    float s0 = 0.f, s1 = 0.f;
    #pragma unroll
    for (int b = 0; b < 16; ++b) { s0 += upart[b*512 + t]; s1 += upart[b*512 + t + 256]; }
    u[t] = s0; u[t + 256] = s1;
    __shared__ float rb[256];
    rb[t] = bo[t] * gw[t] + bo[t + 256] * gw[t + 256];
    __syncthreads();
    for (int s = 128; s > 0; s >>= 1) { if (t < s) rb[t] += rb[t + s]; __syncthreads(); }
    if (t == 0) c0[0] = rb[0] + gb[0];
}

union U8 { unsigned u[4]; short8 s; };

// ---- main: per-graph, wave-per-head, 2 blocks/CU ----
__global__ __launch_bounds__(512, 4)
void attn_ctx_kernel(const float* __restrict__ x,             // [65536,512] f32
                     const unsigned short* __restrict__ wqkv, // [1536,512] bf16
                     const float* __restrict__ bqkv,          // [1536] f32
                     const float* __restrict__ u,             // [512] f32
                     const float* __restrict__ c0,            // [1] f32
                     unsigned short* __restrict__ wctx_ws,    // [1024,512] bf16
                     float* __restrict__ sumgate)             // [1024] f32
{
    __shared__ unsigned short xs[64][520];     // 66560 B; later overlaid w/ scratch
    __shared__ float logitp[8][64];            // 2048 B
    __shared__ float gatev[64];                // 256 B
    // total 68864 B -> 2 blocks/CU, 16 waves/CU (4/SIMD)

    const int g    = blockIdx.x;
    const int tid  = threadIdx.x;
    const int w    = tid >> 6;      // wave = head
    const int lane = tid & 63;
    const int l15  = lane & 15;
    const int quad = lane >> 4;

    // ---- stage x once: fp32 -> bf16 LDS ----
    #pragma unroll
    for (int i = 0; i < 16; ++i) {
        int idx = tid + i * 512;
        int row = idx >> 7;
        int c4  = idx & 127;
        float4 v = *(const float4*)(x + ((size_t)(g*64 + row))*512 + c4*4);
        uint2 p; p.x = pack2(v.x, v.y); p.y = pack2(v.z, v.w);
        *(uint2*)(&xs[row][c4*4]) = p;
    }
    __syncthreads();

    const int h = w;

    // ======== pass-A: q,k (K=512) -> score frags in-register ========
    U8 qA[4][2], kB[4][2];   // [n-strip][ks2]
    #pragma unroll
    for (int dt = 0; dt < 4; ++dt) {
        f32x4 aq[4], ak[4];
        #pragma unroll
        for (int nt = 0; nt < 4; ++nt) {
            aq[nt] = (f32x4){0.f,0.f,0.f,0.f};
            ak[nt] = (f32x4){0.f,0.f,0.f,0.f};
        }
        const unsigned short* wq = wqkv + (size_t)(       h*64 + dt*16 + l15) * 512;
        const unsigned short* wk = wqkv + (size_t)(512 +  h*64 + dt*16 + l15) * 512;
        #pragma unroll 4
        for (int ks = 0; ks < 16; ++ks) {
            const int col = ks*32 + quad*8;
            short8 a0 = *(const short8*)(wq + col);
            short8 a1 = *(const short8*)(wk + col);
            #pragma unroll
            for (int nt = 0; nt < 4; ++nt) {
                short8 b = *(const short8*)(&xs[nt*16 + l15][col]);
                aq[nt] = __builtin_amdgcn_mfma_f32_16x16x32_bf16(a0, b, aq[nt], 0,0,0);
                ak[nt] = __builtin_amdgcn_mfma_f32_16x16x32_bf16(a1, b, ak[nt], 0,0,0);
            }
        }
        float bq[4], bk2[4];
        #pragma unroll
        for (int r = 0; r < 4; ++r) {
            bq[r]  = bqkv[       h*64 + dt*16 + quad*4 + r];
            bk2[r] = bqkv[512 +  h*64 + dt*16 + quad*4 + r];
        }
        const bool take = ((quad >> 1) == (dt & 1));
        const int  ks2  = dt >> 1;
        #pragma unroll
        for (int nt = 0; nt < 4; ++nt) {
            unsigned q01 = pack2(aq[nt][0]+bq[0],  aq[nt][1]+bq[1]);
            unsigned q23 = pack2(aq[nt][2]+bq[2],  aq[nt][3]+bq[3]);
            unsigned k01 = pack2(ak[nt][0]+bk2[0], ak[nt][1]+bk2[1]);
            unsigned k23 = pack2(ak[nt][2]+bk2[2], ak[nt][3]+bk2[3]);
            #pragma unroll
            for (int j = 0; j < 4; ++j) {
                int srcl = ((quad & 1)*2 + (j >> 1))*16 + l15;
                unsigned tq = (unsigned)__shfl((int)((j & 1) ? q23 : q01), srcl);
                unsigned tk = (unsigned)__shfl((int)((j & 1) ? k23 : k01), srcl);
                if (take) { qA[nt][ks2].u[j] = tq; kB[nt][ks2].u[j] = tk; }
            }
        }
    }

    // ======== scores S[n][m] = q.k^T / 8 ========
    f32x4 sacc[4][4];
    #pragma unroll
    for (int a = 0; a < 4; ++a)
        #pragma unroll
        for (int b = 0; b < 4; ++b) sacc[a][b] = (f32x4){0.f,0.f,0.f,0.f};
    #pragma unroll
    for (int ks2 = 0; ks2 < 2; ++ks2)
        #pragma unroll
        for (int a = 0; a < 4; ++a)
            #pragma unroll
            for (int b = 0; b < 4; ++b)
                sacc[a][b] = __builtin_amdgcn_mfma_f32_16x16x32_bf16(
                                 qA[a][ks2].s, kB[b][ks2].s, sacc[a][b], 0,0,0);

    // ======== softmax over m ========
    #pragma unroll
    for (int a = 0; a < 4; ++a) {
        #pragma unroll
        for (int r = 0; r < 4; ++r) {
            float m0 = -1e30f;
            #pragma unroll
            for (int b = 0; b < 4; ++b) { sacc[a][b][r] *= 0.125f; m0 = fmaxf(m0, sacc[a][b][r]); }
            m0 = fmaxf(m0, __shfl_xor(m0, 1));
            m0 = fmaxf(m0, __shfl_xor(m0, 2));
            m0 = fmaxf(m0, __shfl_xor(m0, 4));
            m0 = fmaxf(m0, __shfl_xor(m0, 8));
            float s = 0.f;
            #pragma unroll
            for (int b = 0; b < 4; ++b) { float e = __expf(sacc[a][b][r] - m0); sacc[a][b][r] = e; s += e; }
            s += __shfl_xor(s, 1); s += __shfl_xor(s, 2); s += __shfl_xor(s, 4); s += __shfl_xor(s, 8);
            float inv = 1.0f / s;
            #pragma unroll
            for (int b = 0; b < 4; ++b) sacc[a][b][r] *= inv;
        }
    }
    // pack P to bf16 pairs (frees the fp32 sacc)
    unsigned ppk[4][4][2];
    #pragma unroll
    for (int a = 0; a < 4; ++a)
        #pragma unroll
        for (int b = 0; b < 4; ++b) {
            ppk[a][b][0] = pack2(sacc[a][b][0], sacc[a][b][1]);
            ppk[a][b][1] = pack2(sacc[a][b][2], sacc[a][b][3]);
        }

    // ======== pass-B: v (K=512), packed to bf16 ========
    unsigned avpk[4][4][2];    // [dt][nt][pair]
    #pragma unroll
    for (int dt = 0; dt < 4; ++dt) {
        f32x4 av[4];
        #pragma unroll
        for (int nt = 0; nt < 4; ++nt) av[nt] = (f32x4){0.f,0.f,0.f,0.f};
        const unsigned short* wv = wqkv + (size_t)(1024 + h*64 + dt*16 + l15) * 512;
        #pragma unroll 4
        for (int ks = 0; ks < 16; ++ks) {
            const int col = ks*32 + quad*8;
            short8 a2 = *(const short8*)(wv + col);
            #pragma unroll
            for (int nt = 0; nt < 4; ++nt) {
                short8 b = *(const short8*)(&xs[nt*16 + l15][col]);
                av[nt] = __builtin_amdgcn_mfma_f32_16x16x32_bf16(a2, b, av[nt], 0,0,0);
            }
        }
        float bv2[4];
        #pragma unroll
        for (int r = 0; r < 4; ++r) bv2[r] = bqkv[1024 + h*64 + dt*16 + quad*4 + r];
        #pragma unroll
        for (int nt = 0; nt < 4; ++nt) {
            avpk[dt][nt][0] = pack2(av[nt][0]+bv2[0], av[nt][1]+bv2[1]);
            avpk[dt][nt][1] = pack2(av[nt][2]+bv2[2], av[nt][3]+bv2[3]);
        }
    }

    __syncthreads();   // ALL waves done reading xs -> overlay per-wave scratch
    unsigned short* S = ((unsigned short*)xs) + w*4096;   // 8 KB/wave, swizzled [64][64]

    // ---- vT[d][m] -> scratch ----
    #pragma unroll
    for (int dt = 0; dt < 4; ++dt)
        #pragma unroll
        for (int nt = 0; nt < 4; ++nt)
            #pragma unroll
            for (int p = 0; p < 2; ++p) {
                unsigned uu = avpk[dt][nt][p];
                int d = dt*16 + quad*4 + 2*p;
                int m = nt*16 + l15;
                S[swz(d,   m)] = (unsigned short)(uu & 0xFFFFu);
                S[swz(d+1, m)] = (unsigned short)(uu >> 16);
            }
    U8 vA[4][2];
    #pragma unroll
    for (int dtile = 0; dtile < 4; ++dtile)
        #pragma unroll
        for (int ks2 = 0; ks2 < 2; ++ks2) {
            int row = dtile*16 + l15;
            int ch  = (ks2*4 + quad) ^ (row & 7);
            vA[dtile][ks2].s = *(const short8*)(S + row*64 + ch*8);
        }
    // ---- P[n][m] -> scratch (overwrites vT region; in-order DS after vA reads) ----
    #pragma unroll
    for (int a = 0; a < 4; ++a)
        #pragma unroll
        for (int b = 0; b < 4; ++b)
            #pragma unroll
            for (int p = 0; p < 2; ++p) {
                unsigned uu = ppk[a][b][p];
                int n = a*16 + quad*4 + 2*p;
                int m = b*16 + l15;
                S[swz(n,   m)] = (unsigned short)(uu & 0xFFFFu);
                S[swz(n+1, m)] = (unsigned short)(uu >> 16);
            }
    U8 pB[4][2];
    #pragma unroll
    for (int a = 0; a < 4; ++a)
        #pragma unroll
        for (int ks2 = 0; ks2 < 2; ++ks2) {
            int row = a*16 + l15;
            int ch  = (ks2*4 + quad) ^ (row & 7);
            pB[a][ks2].s = *(const short8*)(S + row*64 + ch*8);
        }

    // ======== PV: ctxT[d][n] ========
    f32x4 cacc[4][4];   // [dtile][a]; lane: d = dtile*16+quad*4+r, n = a*16+l15
    #pragma unroll
    for (int dtile = 0; dtile < 4; ++dtile)
        #pragma unroll
        for (int a = 0; a < 4; ++a) cacc[dtile][a] = (f32x4){0.f,0.f,0.f,0.f};
    #pragma unroll
    for (int ks2 = 0; ks2 < 2; ++ks2)
        #pragma unroll
        for (int dtile = 0; dtile < 4; ++dtile)
            #pragma unroll
            for (int a = 0; a < 4; ++a)
                cacc[dtile][a] = __builtin_amdgcn_mfma_f32_16x16x32_bf16(
                                     vA[dtile][ks2].s, pB[a][ks2].s, cacc[dtile][a], 0,0,0);

    // ======== gate-logit partials ========
    {
        float uv[4][4];
        #pragma unroll
        for (int dtile = 0; dtile < 4; ++dtile)
            #pragma unroll
            for (int r = 0; r < 4; ++r)
                uv[dtile][r] = u[h*64 + dtile*16 + quad*4 + r];
        #pragma unroll
        for (int a = 0; a < 4; ++a) {
            float s = 0.f;
            #pragma unroll
            for (int dtile = 0; dtile < 4; ++dtile)
                #pragma unroll
                for (int r = 0; r < 4; ++r)
                    s += cacc[dtile][a][r] * uv[dtile][r];
            s += __shfl_xor(s, 16); s += __shfl_xor(s, 32);
            if (quad == 0) logitp[w][a*16 + l15] = s;
        }
    }
    __syncthreads();

    if (tid < 64) {
        float lg = c0[0];
        #pragma unroll
        for (int ww = 0; ww < 8; ++ww) lg += logitp[ww][tid];
        float gt = 1.0f / (1.0f + __expf(-lg));
        gatev[tid] = gt;
        float s = gt;
        s += __shfl_xor(s, 1);  s += __shfl_xor(s, 2);  s += __shfl_xor(s, 4);
        s += __shfl_xor(s, 8);  s += __shfl_xor(s, 16); s += __shfl_xor(s, 32);
        if (tid == 0) sumgate[g] = s;
    }
    __syncthreads();

    // ======== wctx[d] = sum_n gate[n] ctx[n][d] ========
    {
        float gv[4];
        #pragma unroll
        for (int a = 0; a < 4; ++a) gv[a] = gatev[a*16 + l15];
        #pragma unroll
        for (int dtile = 0; dtile < 4; ++dtile) {
            float sr[4];
            #pragma unroll
            for (int r = 0; r < 4; ++r) {
                float s = cacc[dtile][0][r]*gv[0] + cacc[dtile][1][r]*gv[1]
                        + cacc[dtile][2][r]*gv[2] + cacc[dtile][3][r]*gv[3];
                s += __shfl_xor(s, 1); s += __shfl_xor(s, 2);
                s += __shfl_xor(s, 4); s += __shfl_xor(s, 8);
                sr[r] = s;
            }
            if (l15 == 0) {
                uint2 pk; pk.x = pack2(sr[0], sr[1]); pk.y = pack2(sr[2], sr[3]);
                *(uint2*)(wctx_ws + (size_t)g*512 + h*64 + dtile*16 + quad*4) = pk;
            }
        }
    }
}

// ---- final out-projection: out[g][e] = wctx[g,:].Wo[e,:] + sumgate[g]*bo[e] ----
__global__ __launch_bounds__(256, 4)
void outproj_kernel(const unsigned short* __restrict__ wo_bf,   // [512,512] bf16
                    const unsigned short* __restrict__ wctx_bf, // [1024,512] bf16
                    const float* __restrict__ bo,               // [512] f32
                    const float* __restrict__ sumgate,          // [1024] f32
                    float* __restrict__ out)                    // [1024,512] f32
{
    const int tid  = threadIdx.x;
    const int w    = tid >> 6;
    const int lane = tid & 63;
    const int l15  = lane & 15;
    const int quad = lane >> 4;
    const int g0   = blockIdx.x * 32;

    f32x4 oac[8][2];
    #pragma unroll
    for (int et = 0; et < 8; ++et)
        #pragma unroll
        for (int mt = 0; mt < 2; ++mt)
            oac[et][mt] = (f32x4){0.f,0.f,0.f,0.f};

    #pragma unroll 4
    for (int ks = 0; ks < 16; ++ks) {
        const int col = ks*32 + quad*8;
        short8 a0 = *(const short8*)(wctx_bf + (size_t)(g0 + l15)*D_      + col);
        short8 a1 = *(const short8*)(wctx_bf + (size_t)(g0 + 16 + l15)*D_ + col);
        #pragma unroll
        for (int et = 0; et < 8; ++et) {
            short8 b = *(const short8*)(wo_bf + (size_t)(w*128 + et*16 + l15)*D_ + col);
            oac[et][0] = __builtin_amdgcn_mfma_f32_16x16x32_bf16(a0, b, oac[et][0], 0,0,0);
            oac[et][1] = __builtin_amdgcn_mfma_f32_16x16x32_bf16(a1, b, oac[et][1], 0,0,0);
        }
    }
    #pragma unroll
    for (int et = 0; et < 8; ++et) {
        const int e = w*128 + et*16 + l15;
        const float bov = bo[e];
        #pragma unroll
        for (int mt = 0; mt < 2; ++mt)
            #pragma unroll
            for (int r = 0; r < 4; ++r) {
                const int gg = g0 + mt*16 + quad*4 + r;
                out[(size_t)gg*D_ + e] = oac[et][mt][r] + sumgate[gg] * bov;
            }
    }
}

extern "C" void kernel_launch(void* const* d_in, const int* in_sizes, int n_in,
                              void* d_out, int out_size, void* d_ws, size_t ws_size,
                              hipStream_t stream) {
    const float* x    = (const float*)d_in[0];
    // d_in[1] = batch (int64) — unused: graphs are equal-sized (64 nodes)
    const float* wqkv = (const float*)d_in[2];
    const float* bqkv = (const float*)d_in[3];
    const float* wo   = (const float*)d_in[4];
    const float* bo   = (const float*)d_in[5];
    const float* gw   = (const float*)d_in[6];
    const float* gb   = (const float*)d_in[7];
    float* out = (float*)d_out;

    char* ws = (char*)d_ws;
    unsigned short* wqkv_bf = (unsigned short*)(ws + WQKV_OFF);
    unsigned short* wo_bf   = (unsigned short*)(ws + WO_OFF);
    float*          upart   = (float*)(ws + UPART_OFF);
    float*          u_ws    = (float*)(ws + U_OFF);
    float*          c0_ws   = (float*)(ws + C0_OFF);
    float*          sg_ws   = (float*)(ws + SG_OFF);
    unsigned short* wctx_ws = (unsigned short*)(ws + WCTX_OFF);

    const int total = in_sizes[0] / D_;  // 65536 nodes
    const int G     = total / 64;        // 1024 graphs

    hipLaunchKernelGGL(convert_and_u, dim3(1040), dim3(256), 0, stream,
                       wqkv, wo, gw, wqkv_bf, upart);
    hipLaunchKernelGGL(finalize_u,    dim3(1),    dim3(256), 0, stream,
                       upart, bo, gw, gb, u_ws, c0_ws);
    hipLaunchKernelGGL(attn_ctx_kernel, dim3(G),  dim3(512), 0, stream,
                       x, wqkv_bf, bqkv, u_ws, c0_ws, wctx_ws, sg_ws);
    hipLaunchKernelGGL(outproj_kernel, dim3(G/32), dim3(256), 0, stream,
                       wo_bf, wctx_ws, bo, sg_ws, out);
}

// Round 8
// 452.211 us; speedup vs baseline: 1.1171x; 1.1171x over previous
//
#include <hip/hip_runtime.h>
#include <stdint.h>

// AttentionReadout: G=1024 x N=64, D=512, H=8, hd=64. fp32 I/O, bf16 MFMA.
// v8: 2 blocks/CU (4 waves/SIMD, 128-VGPR cap) with NO LDS scratch and no
// spills: every MFMA-output -> next-MFMA-input conversion uses the aligned
// in-register shuffle pattern (contraction dim == source register dim):
//   - q,k swapped (C[d][n]) -> score frags  (v6-proven conversion)
//   - scores TRANSPOSED (S^T[m][n], m on regs) -> softmax over regs+quads,
//     P^T -> pA aligned conversion
//   - v non-swapped (C[m][d], m on regs) -> vB aligned conversion
// Register phasing: pass-A ~105, per-a scores ~110, per-dt v+PV ~110 live.
// Out-projection fused as per-thread GEMV epilogue (wctx via LDS overlay).
// v7 lesson: >128 live at 4 waves/SIMD = catastrophic spill (302 MB writes).

typedef __attribute__((ext_vector_type(8))) short short8;   // 8 bf16
typedef __attribute__((ext_vector_type(4))) float f32x4;    // MFMA C/D frag

#define D_ 512

// ---- ws layout (bytes) ----
#define WQKV_OFF   0u          // 1536*512 bf16 = 1572864
#define WO_OFF     1572864u    // 512*512 bf16  = 524288
#define UPART_OFF  2097152u    // 16*512 f32    = 32768
#define U_OFF      2129920u    // 512 f32       = 2048
#define C0_OFF     2131968u    // 64
// total ~2.1 MB

__device__ __forceinline__ unsigned short f2bf(float f) {
    union { float f; unsigned int u; } t; t.f = f;
    unsigned int u = t.u;
    return (unsigned short)((u + 0x7FFFu + ((u >> 16) & 1u)) >> 16);  // RNE
}
__device__ __forceinline__ unsigned pack2(float a, float b) {
    return (unsigned)f2bf(a) | ((unsigned)f2bf(b) << 16);
}
__device__ __forceinline__ float blo(unsigned v) {
    union { unsigned u; float f; } t; t.u = v << 16; return t.f;
}
__device__ __forceinline__ float bhi(unsigned v) {
    union { unsigned u; float f; } t; t.u = v & 0xFFFF0000u; return t.f;
}

// ---- pre-pass 1 (merged): blocks 0..1023 convert weights; 1024..1039 u-partials ----
__global__ __launch_bounds__(256)
void convert_and_u(const float* __restrict__ wqkv, const float* __restrict__ wo,
                   const float* __restrict__ gw,
                   unsigned short* __restrict__ wbf, float* __restrict__ upart) {
    const int b = blockIdx.x;
    const int t = threadIdx.x;
    if (b < 1024) {
        const int i4 = b * 256 + t;          // 262144 float4 total
        float4 v;
        if (i4 < 196608) v = *(const float4*)(wqkv + (size_t)i4 * 4);
        else             v = *(const float4*)(wo   + (size_t)(i4 - 196608) * 4);
        uint2 p; p.x = pack2(v.x, v.y); p.y = pack2(v.z, v.w);
        *(uint2*)(wbf + (size_t)i4 * 4) = p;
    } else {
        const int bb = b - 1024;             // 16 blocks
        float a0 = 0.f, a1 = 0.f;
        #pragma unroll 4
        for (int e = bb * 32; e < bb * 32 + 32; ++e) {
            const float ge = gw[e];
            a0 += wo[(size_t)e * 512 + t]       * ge;
            a1 += wo[(size_t)e * 512 + t + 256] * ge;
        }
        upart[bb * 512 + t] = a0; upart[bb * 512 + t + 256] = a1;
    }
}

// ---- pre-pass 2: u = sum partials; c0 = bo.gw + gb ----
__global__ __launch_bounds__(256)
void finalize_u(const float* __restrict__ upart, const float* __restrict__ bo,
                const float* __restrict__ gw, const float* __restrict__ gb,
                float* __restrict__ u, float* __restrict__ c0) {
    const int t = threadIdx.x;
    float s0 = 0.f, s1 = 0.f;
    #pragma unroll
    for (int b = 0; b < 16; ++b) { s0 += upart[b*512 + t]; s1 += upart[b*512 + t + 256]; }
    u[t] = s0; u[t + 256] = s1;
    __shared__ float rb[256];
    rb[t] = bo[t] * gw[t] + bo[t + 256] * gw[t + 256];
    __syncthreads();
    for (int s = 128; s > 0; s >>= 1) { if (t < s) rb[t] += rb[t + s]; __syncthreads(); }
    if (t == 0) c0[0] = rb[0] + gb[0];
}

union U8 { unsigned u[4]; short8 s; };

// ---- main: per-graph, wave-per-head, fused out-proj ----
__global__ __launch_bounds__(512, 4)
void attn_full_kernel(const float* __restrict__ x,             // [65536,512] f32
                      const unsigned short* __restrict__ wqkv, // [1536,512] bf16
                      const float* __restrict__ bqkv,          // [1536] f32
                      const unsigned short* __restrict__ wo_bf,// [512,512] bf16
                      const float* __restrict__ bo,            // [512] f32
                      const float* __restrict__ u,             // [512] f32
                      const float* __restrict__ c0,            // [1] f32
                      float* __restrict__ out)                 // [1024,512] f32
{
    __shared__ unsigned short xs[64][520];     // 66560 B; epilogue overlays wctx
    __shared__ float logitp[8][64];            // 2048 B
    __shared__ float gatev[64];                // 256 B
    __shared__ float sgs;                      // 4 B
    // total ~68.9 KB -> 2 blocks/CU, 16 waves/CU (4/SIMD)

    const int g    = blockIdx.x;
    const int tid  = threadIdx.x;
    const int w    = tid >> 6;      // wave = head
    const int lane = tid & 63;
    const int l15  = lane & 15;
    const int quad = lane >> 4;

    // ---- stage x once: fp32 -> bf16 LDS ----
    #pragma unroll
    for (int i = 0; i < 16; ++i) {
        int idx = tid + i * 512;
        int row = idx >> 7;
        int c4  = idx & 127;
        float4 v = *(const float4*)(x + ((size_t)(g*64 + row))*512 + c4*4);
        uint2 p; p.x = pack2(v.x, v.y); p.y = pack2(v.z, v.w);
        *(uint2*)(&xs[row][c4*4]) = p;
    }
    __syncthreads();

    const int h = w;

    // ======== pass-A: q,k (K=512) -> score frags in-register (v6-proven) ========
    U8 qA[4][2], kB[4][2];   // [n-strip][ks2]; rows=n(m), k=d
    #pragma unroll
    for (int dt = 0; dt < 4; ++dt) {
        f32x4 aq[4], ak[4];
        #pragma unroll
        for (int nt = 0; nt < 4; ++nt) {
            aq[nt] = (f32x4){0.f,0.f,0.f,0.f};
            ak[nt] = (f32x4){0.f,0.f,0.f,0.f};
        }
        const unsigned short* wq = wqkv + (size_t)(       h*64 + dt*16 + l15) * 512;
        const unsigned short* wk = wqkv + (size_t)(512 +  h*64 + dt*16 + l15) * 512;
        #pragma unroll 4
        for (int ks = 0; ks < 16; ++ks) {
            const int col = ks*32 + quad*8;
            short8 a0 = *(const short8*)(wq + col);
            short8 a1 = *(const short8*)(wk + col);
            #pragma unroll
            for (int nt = 0; nt < 4; ++nt) {
                short8 b = *(const short8*)(&xs[nt*16 + l15][col]);
                aq[nt] = __builtin_amdgcn_mfma_f32_16x16x32_bf16(a0, b, aq[nt], 0,0,0);
                ak[nt] = __builtin_amdgcn_mfma_f32_16x16x32_bf16(a1, b, ak[nt], 0,0,0);
            }
        }
        float bq[4], bk2[4];
        #pragma unroll
        for (int r = 0; r < 4; ++r) {
            bq[r]  = bqkv[       h*64 + dt*16 + quad*4 + r];
            bk2[r] = bqkv[512 +  h*64 + dt*16 + quad*4 + r];
        }
        const bool take = ((quad >> 1) == (dt & 1));
        const int  ks2  = dt >> 1;
        #pragma unroll
        for (int nt = 0; nt < 4; ++nt) {
            unsigned q01 = pack2(aq[nt][0]+bq[0],  aq[nt][1]+bq[1]);
            unsigned q23 = pack2(aq[nt][2]+bq[2],  aq[nt][3]+bq[3]);
            unsigned k01 = pack2(ak[nt][0]+bk2[0], ak[nt][1]+bk2[1]);
            unsigned k23 = pack2(ak[nt][2]+bk2[2], ak[nt][3]+bk2[3]);
            #pragma unroll
            for (int j = 0; j < 4; ++j) {
                int srcl = ((quad & 1)*2 + (j >> 1))*16 + l15;
                unsigned tq = (unsigned)__shfl((int)((j & 1) ? q23 : q01), srcl);
                unsigned tk = (unsigned)__shfl((int)((j & 1) ? k23 : k01), srcl);
                if (take) { qA[nt][ks2].u[j] = tq; kB[nt][ks2].u[j] = tk; }
            }
        }
    }

    // ======== scores (TRANSPOSED) + softmax + P^T->pA, per n-tile a ========
    // sacc[b] = S^T tile: m = b*16 + quad*4 + r (regs), n = a*16 + l15 (lanes)
    U8 pA[4][2];   // A-frag for PV: rows n, k = m
    #pragma unroll
    for (int a = 0; a < 4; ++a) {
        f32x4 sc[4];
        #pragma unroll
        for (int b = 0; b < 4; ++b) sc[b] = (f32x4){0.f,0.f,0.f,0.f};
        #pragma unroll
        for (int ks2 = 0; ks2 < 2; ++ks2)
            #pragma unroll
            for (int b = 0; b < 4; ++b)
                sc[b] = __builtin_amdgcn_mfma_f32_16x16x32_bf16(
                            kB[b][ks2].s, qA[a][ks2].s, sc[b], 0,0,0);
        // softmax over m = (b, r, quad); row n = a*16 + l15
        float m0 = -1e30f;
        #pragma unroll
        for (int b = 0; b < 4; ++b)
            #pragma unroll
            for (int r = 0; r < 4; ++r) { sc[b][r] *= 0.125f; m0 = fmaxf(m0, sc[b][r]); }
        m0 = fmaxf(m0, __shfl_xor(m0, 16));
        m0 = fmaxf(m0, __shfl_xor(m0, 32));
        float ssum = 0.f;
        #pragma unroll
        for (int b = 0; b < 4; ++b)
            #pragma unroll
            for (int r = 0; r < 4; ++r) { float e = __expf(sc[b][r] - m0); sc[b][r] = e; ssum += e; }
        ssum += __shfl_xor(ssum, 16);
        ssum += __shfl_xor(ssum, 32);
        float inv = 1.0f / ssum;
        // pack P^T pairs (over m-register dim) and convert to pA (aligned pattern)
        unsigned pp[4][2];
        #pragma unroll
        for (int b = 0; b < 4; ++b) {
            pp[b][0] = pack2(sc[b][0]*inv, sc[b][1]*inv);
            pp[b][1] = pack2(sc[b][2]*inv, sc[b][3]*inv);
        }
        #pragma unroll
        for (int ks2 = 0; ks2 < 2; ++ks2)
            #pragma unroll
            for (int j = 0; j < 4; ++j) {
                int srcl = ((quad & 1)*2 + (j >> 1))*16 + l15;
                unsigned t0 = (unsigned)__shfl((int)pp[ks2*2    ][j & 1], srcl);
                unsigned t1 = (unsigned)__shfl((int)pp[ks2*2 + 1][j & 1], srcl);
                pA[a][ks2].u[j] = (quad >> 1) ? t1 : t0;
            }
    }

    // ======== pass-B: v (non-swapped C[m][d]) + convert + PV, per d-tile dt ========
    f32x4 cacc[4][4];   // [a][dt]: n = a*16 + quad*4 + r, d = dt*16 + l15
    #pragma unroll
    for (int a = 0; a < 4; ++a)
        #pragma unroll
        for (int dt = 0; dt < 4; ++dt) cacc[a][dt] = (f32x4){0.f,0.f,0.f,0.f};
    #pragma unroll
    for (int dt = 0; dt < 4; ++dt) {
        f32x4 av[4];
        #pragma unroll
        for (int mt = 0; mt < 4; ++mt) av[mt] = (f32x4){0.f,0.f,0.f,0.f};
        const unsigned short* wv = wqkv + (size_t)(1024 + h*64 + dt*16 + l15) * 512;
        #pragma unroll 4
        for (int ks = 0; ks < 16; ++ks) {
            const int col = ks*32 + quad*8;
            short8 a2 = *(const short8*)(wv + col);
            #pragma unroll
            for (int mt = 0; mt < 4; ++mt) {
                short8 b = *(const short8*)(&xs[mt*16 + l15][col]);
                // A = x rows (m), B = wv rows (d) -> C[m][d]
                av[mt] = __builtin_amdgcn_mfma_f32_16x16x32_bf16(b, a2, av[mt], 0,0,0);
            }
        }
        const float bv = bqkv[1024 + h*64 + dt*16 + l15];   // bias indexed by d = lane
        unsigned vpk[4][2];
        #pragma unroll
        for (int mt = 0; mt < 4; ++mt) {
            vpk[mt][0] = pack2(av[mt][0]+bv, av[mt][1]+bv);
            vpk[mt][1] = pack2(av[mt][2]+bv, av[mt][3]+bv);
        }
        U8 vB[2];   // B-frag: rows d, k = m
        #pragma unroll
        for (int ks2 = 0; ks2 < 2; ++ks2)
            #pragma unroll
            for (int j = 0; j < 4; ++j) {
                int srcl = ((quad & 1)*2 + (j >> 1))*16 + l15;
                unsigned t0 = (unsigned)__shfl((int)vpk[ks2*2    ][j & 1], srcl);
                unsigned t1 = (unsigned)__shfl((int)vpk[ks2*2 + 1][j & 1], srcl);
                vB[ks2].u[j] = (quad >> 1) ? t1 : t0;
            }
        #pragma unroll
        for (int ks2 = 0; ks2 < 2; ++ks2)
            #pragma unroll
            for (int a = 0; a < 4; ++a)
                cacc[a][dt] = __builtin_amdgcn_mfma_f32_16x16x32_bf16(
                                  pA[a][ks2].s, vB[ks2].s, cacc[a][dt], 0,0,0);
    }

    // ======== gate-logit partials: logit[n] = sum_d ctx[n][d] u[h*64+d] ========
    {
        float ul[4];
        #pragma unroll
        for (int dt = 0; dt < 4; ++dt) ul[dt] = u[h*64 + dt*16 + l15];
        #pragma unroll
        for (int a = 0; a < 4; ++a)
            #pragma unroll
            for (int r = 0; r < 4; ++r) {
                float s = cacc[a][0][r]*ul[0] + cacc[a][1][r]*ul[1]
                        + cacc[a][2][r]*ul[2] + cacc[a][3][r]*ul[3];
                s += __shfl_xor(s, 1); s += __shfl_xor(s, 2);
                s += __shfl_xor(s, 4); s += __shfl_xor(s, 8);   // sum over l15 (d within tile)
                if (l15 == 0) logitp[w][a*16 + quad*4 + r] = s;
            }
    }
    __syncthreads();

    if (tid < 64) {
        float lg = c0[0];
        #pragma unroll
        for (int ww = 0; ww < 8; ++ww) lg += logitp[ww][tid];
        float gt = 1.0f / (1.0f + __expf(-lg));
        gatev[tid] = gt;
        float s = gt;
        s += __shfl_xor(s, 1);  s += __shfl_xor(s, 2);  s += __shfl_xor(s, 4);
        s += __shfl_xor(s, 8);  s += __shfl_xor(s, 16); s += __shfl_xor(s, 32);
        if (tid == 0) sgs = s;
    }
    __syncthreads();

    // ======== wctx[d] = sum_n gate[n] ctx[n][d] -> LDS overlay on xs ========
    float* wctxs = (float*)&xs[0][0];   // 512 f32 (xs dead)
    {
        float4 gv[4];
        #pragma unroll
        for (int a = 0; a < 4; ++a) gv[a] = *(const float4*)&gatev[a*16 + quad*4];
        #pragma unroll
        for (int dt = 0; dt < 4; ++dt) {
            float s = 0.f;
            #pragma unroll
            for (int a = 0; a < 4; ++a) {
                s += cacc[a][dt][0]*gv[a].x + cacc[a][dt][1]*gv[a].y
                   + cacc[a][dt][2]*gv[a].z + cacc[a][dt][3]*gv[a].w;
            }
            s += __shfl_xor(s, 16); s += __shfl_xor(s, 32);   // sum over quads (n-groups)
            if (quad == 0) wctxs[h*64 + dt*16 + l15] = s;
        }
    }
    __syncthreads();

    // ======== fused out-projection GEMV: out[g][e] = wctx.Wo[e,:] + sgs*bo[e] ========
    {
        const unsigned short* wr = wo_bf + (size_t)tid * 512;   // row e = tid
        float acc = 0.f;
        #pragma unroll 8
        for (int i = 0; i < 64; ++i) {
            uint4  w4 = *(const uint4*)(wr + i*8);
            float4 ca = *(const float4*)(wctxs + i*8);
            float4 cb = *(const float4*)(wctxs + i*8 + 4);
            acc += blo(w4.x)*ca.x + bhi(w4.x)*ca.y + blo(w4.y)*ca.z + bhi(w4.y)*ca.w
                 + blo(w4.z)*cb.x + bhi(w4.z)*cb.y + blo(w4.w)*cb.z + bhi(w4.w)*cb.w;
        }
        out[(size_t)g*512 + tid] = acc + sgs * bo[tid];
    }
}

extern "C" void kernel_launch(void* const* d_in, const int* in_sizes, int n_in,
                              void* d_out, int out_size, void* d_ws, size_t ws_size,
                              hipStream_t stream) {
    const float* x    = (const float*)d_in[0];
    // d_in[1] = batch (int64) — unused: graphs are equal-sized (64 nodes)
    const float* wqkv = (const float*)d_in[2];
    const float* bqkv = (const float*)d_in[3];
    const float* wo   = (const float*)d_in[4];
    const float* bo   = (const float*)d_in[5];
    const float* gw   = (const float*)d_in[6];
    const float* gb   = (const float*)d_in[7];
    float* out = (float*)d_out;

    char* ws = (char*)d_ws;
    unsigned short* wqkv_bf = (unsigned short*)(ws + WQKV_OFF);
    unsigned short* wo_bf   = (unsigned short*)(ws + WO_OFF);
    float*          upart   = (float*)(ws + UPART_OFF);
    float*          u_ws    = (float*)(ws + U_OFF);
    float*          c0_ws   = (float*)(ws + C0_OFF);

    const int total = in_sizes[0] / D_;  // 65536 nodes
    const int G     = total / 64;        // 1024 graphs

    hipLaunchKernelGGL(convert_and_u, dim3(1040), dim3(256), 0, stream,
                       wqkv, wo, gw, wqkv_bf, upart);
    hipLaunchKernelGGL(finalize_u,    dim3(1),    dim3(256), 0, stream,
                       upart, bo, gw, gb, u_ws, c0_ws);
    hipLaunchKernelGGL(attn_full_kernel, dim3(G), dim3(512), 0, stream,
                       x, wqkv_bf, bqkv, wo_bf, bo, u_ws, c0_ws, out);
}